// Round 8
// baseline (775.249 us; speedup 1.0000x reference)
//
#include <hip/hip_runtime.h>
#include <hip/hip_bf16.h>

#define B_   8
#define C1_  256
#define C2_  256
#define Cm_  128    // C_ = C2/2
#define H_   80
#define W_   80
#define HW_  6400
#define CN_  1152   // C_ * 9
#define EPS_ 1e-5f

#define CH_   32    // channels per K-chunk in fused kernel
#define NCHK_ 4     // chunks (128/32)
#define NPX_  40    // real pixels per block (half row)
#define NPAD_ 48    // padded to 3 n-frags
#define VSTR_ 288   // vbuf row = 9*CH_ shorts; 144 dw == 16 mod 32 (disjoint half-wave banks)

typedef __attribute__((ext_vector_type(8))) short bf16x8;
typedef __attribute__((ext_vector_type(4))) float f32x4;

__device__ inline unsigned short f2bf(float f) {
  union { float f; unsigned int u; } v; v.f = f;
  unsigned int u = v.u;
  unsigned int r = (u + 0x7FFFu + ((u >> 16) & 1u)) >> 16;
  return (unsigned short)r;
}
__device__ inline float bf2f(unsigned short s) {
  union { unsigned int u; float f; } v; v.u = ((unsigned int)s) << 16;
  return v.f;
}

// ---- Kernel 0: prep — Wc->bf16 K-permuted, BN-folded Wg', BN2 scale/shift --
// Wcb[o][n*128+c] = Wc[o][c*9+n];  Wgf[c][o][i] = Wg*sg;  bgf = folded bias
__global__ __launch_bounds__(256) void k0_prep(
    const float* __restrict__ Wc, const float* __restrict__ bc,
    const float* __restrict__ g2, const float* __restrict__ b2,
    const float* __restrict__ m2, const float* __restrict__ v2,
    const float* __restrict__ Wg, const float* __restrict__ bg,
    const float* __restrict__ gg, const float* __restrict__ bgw,
    const float* __restrict__ mg, const float* __restrict__ vg,
    unsigned short* __restrict__ Wcb, float* __restrict__ A2,
    float* __restrict__ B2, float* __restrict__ Wgf,
    float* __restrict__ bgf) {
  int idx = blockIdx.x * 256 + threadIdx.x;
  if (idx < C2_ * CN_) {
    int o = idx / CN_;
    int r = idx - o * CN_;
    int n = r >> 7;          // 0..8
    int c = r & 127;         // 0..127
    Wcb[idx] = f2bf(Wc[o * CN_ + c * 9 + n]);
  }
  if (idx < Cm_ * 81) {
    int c  = idx / 81;
    int oi = idx - c * 81;
    int o  = oi / 9;
    float sg = gg[c * 9 + o] * rsqrtf(vg[c * 9 + o] + EPS_);
    Wgf[idx] = Wg[idx] * sg;
  }
  if (idx < Cm_ * 9) {
    float sg = gg[idx] * rsqrtf(vg[idx] + EPS_);
    bgf[idx] = (bg[idx] - mg[idx]) * sg + bgw[idx];
  }
  if (idx < C2_) {
    float s = g2[idx] * rsqrtf(v2[idx] + EPS_);
    A2[idx] = s;
    B2[idx] = (bc[idx] - m2[idx]) * s + b2[idx];
  }
}

// ---------------- Kernel 1: h = SiLU(BN1(W1 @ x)), bf16 out -----------------
__global__ __launch_bounds__(256) void k1_cv1(
    const float* __restrict__ x, const float* __restrict__ W1,
    const float* __restrict__ g1, const float* __restrict__ b1,
    const float* __restrict__ m1, const float* __restrict__ v1,
    unsigned short* __restrict__ h) {
  __shared__ float ws[16][128];
  __shared__ float xs[16][128];
  const int b   = blockIdx.y;
  const int hw0 = blockIdx.x * 128;
  const int t   = threadIdx.x;
  const int tn  = t & 15;
  const int tm  = t >> 4;

  float acc[8][8];
#pragma unroll
  for (int i = 0; i < 8; ++i)
#pragma unroll
    for (int j = 0; j < 8; ++j) acc[i][j] = 0.f;

  const int m_l = t & 127;
  for (int c0 = 0; c0 < C1_; c0 += 16) {
#pragma unroll
    for (int i = 0; i < 8; ++i) {
      int idx = t + i * 256;
      int kk = idx >> 7;
      ws[kk][m_l] = W1[m_l * C1_ + c0 + kk];
    }
#pragma unroll
    for (int i = 0; i < 8; ++i) {
      int idx = t + i * 256;
      int kk = idx >> 7;
      xs[kk][m_l] = x[((size_t)b * C1_ + c0 + kk) * HW_ + hw0 + m_l];
    }
    __syncthreads();
#pragma unroll
    for (int kk = 0; kk < 16; ++kk) {
      float av[8], bv[8];
      *reinterpret_cast<float4*>(&av[0]) = *reinterpret_cast<const float4*>(&ws[kk][tm * 8]);
      *reinterpret_cast<float4*>(&av[4]) = *reinterpret_cast<const float4*>(&ws[kk][tm * 8 + 4]);
      *reinterpret_cast<float4*>(&bv[0]) = *reinterpret_cast<const float4*>(&xs[kk][tn * 8]);
      *reinterpret_cast<float4*>(&bv[4]) = *reinterpret_cast<const float4*>(&xs[kk][tn * 8 + 4]);
#pragma unroll
      for (int i = 0; i < 8; ++i)
#pragma unroll
        for (int j = 0; j < 8; ++j)
          acc[i][j] = fmaf(av[i], bv[j], acc[i][j]);
    }
    __syncthreads();
  }
#pragma unroll
  for (int i = 0; i < 8; ++i) {
    int o = tm * 8 + i;
    float s  = g1[o] * rsqrtf(v1[o] + EPS_);
    float sh = b1[o] - m1[o] * s;
    unsigned short pk[8];
#pragma unroll
    for (int j = 0; j < 8; ++j) {
      float val = fmaf(acc[i][j], s, sh);
      float sig = 1.f / (1.f + __expf(-val));
      pk[j] = f2bf(val * sig);
    }
    uint4* dst = reinterpret_cast<uint4*>(
        h + ((size_t)b * Cm_ + o) * HW_ + hw0 + tn * 8);
    *dst = *reinterpret_cast<const uint4*>(pk);
  }
}

// ---------------- Kernel 2 (fused v2) ---------------------------------------
// grid: (2, H, B), block 256 (4 waves). Block = 40-px half row (N padded 48).
// Per 32-ch chunk: stage {halo, Wg', bias'} -> vectorized weights/softmax into
// K-permuted vbuf -> MFMA K-slice. All LDS access conflict-free by design.
__global__ __launch_bounds__(256) void k2f(
    const unsigned short* __restrict__ h,
    const float* __restrict__ Wgf, const float* __restrict__ bgf,
    const unsigned short* __restrict__ Wcb,
    const float* __restrict__ A2, const float* __restrict__ B2,
    const float* __restrict__ x, float* __restrict__ out) {
  __shared__ alignas(16) unsigned short ht[CH_ * 3 * 48];   // 9216 B
  __shared__ alignas(16) unsigned short vbuf[NPAD_][VSTR_]; // 27648 B
  __shared__ alignas(16) float wgs[CH_ * 108];              // [c][n][12], 13824 B
  __shared__ float bgs[CH_ * 9];                            // 1152 B

  const int half = blockIdx.x;
  const int y    = blockIdx.y;
  const int b    = blockIdx.z;
  const int x0   = half * NPX_;
  const int t    = threadIdx.x;
  const int w    = __builtin_amdgcn_readfirstlane(t >> 6);
  const int l15  = t & 15;
  const int lhi  = (t & 63) >> 4;

  const int c_w = t & 31;        // weights role
  const int g_w = t >> 5;        // px-group 0..4 active, 5..7 idle
  const int par = g_w & 1;

  f32x4 acc[4][3];
#pragma unroll
  for (int i = 0; i < 4; ++i)
#pragma unroll
    for (int nf = 0; nf < 3; ++nf) acc[i][nf] = (f32x4)0.f;

  for (int ch = 0; ch < NCHK_; ++ch) {
    // ---- stage: h halo (zero-padded), Wg' chunk, bias' chunk ----
    for (int idx = t; idx < CH_ * 3 * 48; idx += 256) {
      int c   = idx / 144;
      int rem = idx - c * 144;
      int r   = rem / 48;
      int col = rem - r * 48;
      int gy  = y + r - 1;
      int gx  = x0 + col - 1;
      unsigned short v = 0;
      if (col < 42 && (unsigned)gy < (unsigned)H_ && (unsigned)gx < (unsigned)W_)
        v = h[((size_t)b * Cm_ + ch * CH_ + c) * HW_ + gy * W_ + gx];
      ht[idx] = v;
    }
    for (int idx = t; idx < CH_ * 81; idx += 256) {
      int c   = idx / 81;
      int rem = idx - c * 81;
      int n   = rem / 9;
      int i   = rem - n * 9;
      wgs[c * 108 + n * 12 + i] = Wgf[(ch * CH_ + c) * 81 + rem];
    }
    if (t < CH_ * 9) bgs[t] = bgf[ch * CH_ * 9 + t];
    __syncthreads();

    // ---- weights: vectorized 9->9 mix + softmax -> vbuf[px][n*32+c] ----
    if (g_w < 5) {
      // load 3 halo rows x 10 cols (2x b128 each), convert once
      float f[3][10];
#pragma unroll
      for (int r = 0; r < 3; ++r) {
        bf16x8 r0 = *reinterpret_cast<const bf16x8*>(&ht[(c_w * 3 + r) * 48 + g_w * 8]);
        bf16x8 r1 = *reinterpret_cast<const bf16x8*>(&ht[(c_w * 3 + r) * 48 + g_w * 8 + 8]);
#pragma unroll
        for (int u = 0; u < 8; ++u) f[r][u] = bf2f((unsigned short)r0[u]);
        f[r][8] = bf2f((unsigned short)r1[0]);
        f[r][9] = bf2f((unsigned short)r1[1]);
      }
      float bias9[9];
#pragma unroll
      for (int n = 0; n < 9; ++n) bias9[n] = bgs[c_w * 9 + n];

#pragma unroll
      for (int j = 0; j < 8; ++j) {
        int q  = (j + 3 * par) & 7;            // rotation: half-waves hit disjoint banks
        int px = g_w * 8 + q;
        float p[9];
#pragma unroll
        for (int i = 0; i < 3; ++i)
#pragma unroll
          for (int jj = 0; jj < 3; ++jj)
            p[i * 3 + jj] = f[i][q + jj];
        float wv[9];
#pragma unroll
        for (int n = 0; n < 9; ++n) {
          float4 w0 = *reinterpret_cast<const float4*>(&wgs[c_w * 108 + n * 12]);
          float4 w1 = *reinterpret_cast<const float4*>(&wgs[c_w * 108 + n * 12 + 4]);
          float w8  = wgs[c_w * 108 + n * 12 + 8];
          float a = bias9[n];
          a = fmaf(w0.x, p[0], a); a = fmaf(w0.y, p[1], a);
          a = fmaf(w0.z, p[2], a); a = fmaf(w0.w, p[3], a);
          a = fmaf(w1.x, p[4], a); a = fmaf(w1.y, p[5], a);
          a = fmaf(w1.z, p[6], a); a = fmaf(w1.w, p[7], a);
          a = fmaf(w8,   p[8], a);
          wv[n] = a;
        }
        float mx = wv[0];
#pragma unroll
        for (int n = 1; n < 9; ++n) mx = fmaxf(mx, wv[n]);
        float sum = 0.f;
#pragma unroll
        for (int n = 0; n < 9; ++n) { wv[n] = __expf(wv[n] - mx); sum += wv[n]; }
        float inv = 1.f / sum;
#pragma unroll
        for (int n = 0; n < 9; ++n)
          vbuf[px][n * CH_ + c_w] = f2bf(p[n] * wv[n] * inv);
      }
    }
    __syncthreads();

    // ---- MFMA: 9 k-steps of 32 (K-permuted: k = n*128 + ch*32 + c) ----
#pragma unroll
    for (int ks = 0; ks < 9; ++ks) {
      bf16x8 av[4], bv[3];
#pragma unroll
      for (int i = 0; i < 4; ++i)
        av[i] = *reinterpret_cast<const bf16x8*>(
            Wcb + (size_t)(w * 64 + i * 16 + l15) * CN_ + ks * 128 + ch * CH_ + 8 * lhi);
#pragma unroll
      for (int nf = 0; nf < 3; ++nf)
        bv[nf] = *reinterpret_cast<const bf16x8*>(
            &vbuf[nf * 16 + l15][ks * CH_ + 8 * lhi]);
#pragma unroll
      for (int i = 0; i < 4; ++i)
#pragma unroll
        for (int nf = 0; nf < 3; ++nf)
          acc[i][nf] = __builtin_amdgcn_mfma_f32_16x16x32_bf16(
              av[i], bv[nf], acc[i][nf], 0, 0, 0);
    }
    __syncthreads();
  }

  // ---- epilogue: BN2 + ReLU + residual (guard px < 40) ----
#pragma unroll
  for (int i = 0; i < 4; ++i) {
#pragma unroll
    for (int r = 0; r < 4; ++r) {
      int o = w * 64 + i * 16 + lhi * 4 + r;
      float sA = A2[o], sB = B2[o];
#pragma unroll
      for (int nf = 0; nf < 3; ++nf) {
        int px = nf * 16 + l15;
        if (px < NPX_) {
          float val = fmaf(acc[i][nf][r], sA, sB);
          val = fmaxf(val, 0.f);
          size_t idx = ((size_t)b * C2_ + o) * HW_ + y * W_ + x0 + px;
          out[idx] = x[idx] + val;
        }
      }
    }
  }
}

extern "C" void kernel_launch(void* const* d_in, const int* in_sizes, int n_in,
                              void* d_out, int out_size, void* d_ws, size_t ws_size,
                              hipStream_t stream) {
  (void)in_sizes; (void)n_in; (void)out_size; (void)ws_size;
  const float* x   = (const float*)d_in[0];
  const float* W1  = (const float*)d_in[1];
  const float* g1  = (const float*)d_in[2];
  const float* b1  = (const float*)d_in[3];
  const float* m1  = (const float*)d_in[4];
  const float* v1  = (const float*)d_in[5];
  const float* Wg  = (const float*)d_in[6];
  const float* bg  = (const float*)d_in[7];
  const float* gg  = (const float*)d_in[8];
  const float* bgw = (const float*)d_in[9];
  const float* mg  = (const float*)d_in[10];
  const float* vg  = (const float*)d_in[11];
  const float* Wc  = (const float*)d_in[12];
  const float* bc  = (const float*)d_in[13];
  const float* g2  = (const float*)d_in[14];
  const float* b2  = (const float*)d_in[15];
  const float* m2  = (const float*)d_in[16];
  const float* v2  = (const float*)d_in[17];
  float* outp = (float*)d_out;

  // workspace layout (bytes):
  //   h   : bf16 [8][128][6400]   13,107,200
  //   Wcb : bf16 [256][1152]         589,824 (K-permuted)
  //   Wgf : f32  [128][81]            41,472 (BN-folded)
  //   bgf : f32  [128][9]              4,608
  //   A2,B2: f32 [256] each            2,048
  char* ws = (char*)d_ws;
  unsigned short* h   = (unsigned short*)ws;
  unsigned short* Wcb = (unsigned short*)(ws + 13107200);
  float*          Wgf = (float*)(ws + 13107200 + 589824);
  float*          bgf = (float*)(ws + 13107200 + 589824 + 41472);
  float*          A2  = (float*)(ws + 13107200 + 589824 + 41472 + 4608);
  float*          B2  = A2 + C2_;

  k0_prep<<<dim3((C2_ * CN_ + 255) / 256), 256, 0, stream>>>(
      Wc, bc, g2, b2, m2, v2, Wg, bg, gg, bgw, mg, vg, Wcb, A2, B2, Wgf, bgf);

  dim3 grid1(HW_ / 128, B_);
  k1_cv1<<<grid1, 256, 0, stream>>>(x, W1, g1, b1, m1, v1, h);

  dim3 grid2(2, H_, B_);
  k2f<<<grid2, 256, 0, stream>>>(h, Wgf, bgf, Wcb, A2, B2, x, outp);
}

// Round 9
// 324.956 us; speedup vs baseline: 2.3857x; 2.3857x over previous
//
#include <hip/hip_runtime.h>
#include <hip/hip_bf16.h>

#define B_   8
#define C1_  256
#define C2_  256
#define Cm_  128    // C_ = C2/2
#define H_   80
#define W_   80
#define HW_  6400
#define CN_  1152   // C_ * 9
#define EPS_ 1e-5f

typedef __attribute__((ext_vector_type(8))) short bf16x8;
typedef __attribute__((ext_vector_type(4))) float f32x4;

__device__ inline unsigned short f2bf(float f) {
  union { float f; unsigned int u; } v; v.f = f;
  unsigned int u = v.u;
  unsigned int r = (u + 0x7FFFu + ((u >> 16) & 1u)) >> 16;
  return (unsigned short)r;
}
__device__ inline float bf2f(unsigned short s) {
  union { unsigned int u; float f; } v; v.u = ((unsigned int)s) << 16;
  return v.f;
}

// ---- Kernel 0: prep — Wc->bf16 K-permuted, BN-folded Wg', BN2 scale/shift --
// Wcb[o][n*128+c] = Wc[o][c*9+n];  Wgf[c][n][i] = Wg*sg;  bgf = folded bias
__global__ __launch_bounds__(256) void k0_prep(
    const float* __restrict__ Wc, const float* __restrict__ bc,
    const float* __restrict__ g2, const float* __restrict__ b2,
    const float* __restrict__ m2, const float* __restrict__ v2,
    const float* __restrict__ Wg, const float* __restrict__ bg,
    const float* __restrict__ gg, const float* __restrict__ bgw,
    const float* __restrict__ mg, const float* __restrict__ vg,
    unsigned short* __restrict__ Wcb, float* __restrict__ A2,
    float* __restrict__ B2, float* __restrict__ Wgf,
    float* __restrict__ bgf) {
  int idx = blockIdx.x * 256 + threadIdx.x;
  if (idx < C2_ * CN_) {
    int o = idx / CN_;
    int r = idx - o * CN_;
    int n = r >> 7;          // 0..8
    int c = r & 127;         // 0..127
    Wcb[idx] = f2bf(Wc[o * CN_ + c * 9 + n]);
  }
  if (idx < Cm_ * 81) {
    int c  = idx / 81;
    int oi = idx - c * 81;
    int o  = oi / 9;
    float sg = gg[c * 9 + o] * rsqrtf(vg[c * 9 + o] + EPS_);
    Wgf[idx] = Wg[idx] * sg;
  }
  if (idx < Cm_ * 9) {
    float sg = gg[idx] * rsqrtf(vg[idx] + EPS_);
    bgf[idx] = (bg[idx] - mg[idx]) * sg + bgw[idx];
  }
  if (idx < C2_) {
    float s = g2[idx] * rsqrtf(v2[idx] + EPS_);
    A2[idx] = s;
    B2[idx] = (bc[idx] - m2[idx]) * s + b2[idx];
  }
}

// ---------------- Kernel 1: h = SiLU(BN1(W1 @ x)), bf16 out -----------------
__global__ __launch_bounds__(256) void k1_cv1(
    const float* __restrict__ x, const float* __restrict__ W1,
    const float* __restrict__ g1, const float* __restrict__ b1,
    const float* __restrict__ m1, const float* __restrict__ v1,
    unsigned short* __restrict__ h) {
  __shared__ float ws[16][128];
  __shared__ float xs[16][128];
  const int b   = blockIdx.y;
  const int hw0 = blockIdx.x * 128;
  const int t   = threadIdx.x;
  const int tn  = t & 15;
  const int tm  = t >> 4;

  float acc[8][8];
#pragma unroll
  for (int i = 0; i < 8; ++i)
#pragma unroll
    for (int j = 0; j < 8; ++j) acc[i][j] = 0.f;

  const int m_l = t & 127;
  for (int c0 = 0; c0 < C1_; c0 += 16) {
#pragma unroll
    for (int i = 0; i < 8; ++i) {
      int idx = t + i * 256;
      int kk = idx >> 7;
      ws[kk][m_l] = W1[m_l * C1_ + c0 + kk];
    }
#pragma unroll
    for (int i = 0; i < 8; ++i) {
      int idx = t + i * 256;
      int kk = idx >> 7;
      xs[kk][m_l] = x[((size_t)b * C1_ + c0 + kk) * HW_ + hw0 + m_l];
    }
    __syncthreads();
#pragma unroll
    for (int kk = 0; kk < 16; ++kk) {
      float av[8], bv[8];
      *reinterpret_cast<float4*>(&av[0]) = *reinterpret_cast<const float4*>(&ws[kk][tm * 8]);
      *reinterpret_cast<float4*>(&av[4]) = *reinterpret_cast<const float4*>(&ws[kk][tm * 8 + 4]);
      *reinterpret_cast<float4*>(&bv[0]) = *reinterpret_cast<const float4*>(&xs[kk][tn * 8]);
      *reinterpret_cast<float4*>(&bv[4]) = *reinterpret_cast<const float4*>(&xs[kk][tn * 8 + 4]);
#pragma unroll
      for (int i = 0; i < 8; ++i)
#pragma unroll
        for (int j = 0; j < 8; ++j)
          acc[i][j] = fmaf(av[i], bv[j], acc[i][j]);
    }
    __syncthreads();
  }
#pragma unroll
  for (int i = 0; i < 8; ++i) {
    int o = tm * 8 + i;
    float s  = g1[o] * rsqrtf(v1[o] + EPS_);
    float sh = b1[o] - m1[o] * s;
    unsigned short pk[8];
#pragma unroll
    for (int j = 0; j < 8; ++j) {
      float val = fmaf(acc[i][j], s, sh);
      float sig = 1.f / (1.f + __expf(-val));
      pk[j] = f2bf(val * sig);
    }
    uint4* dst = reinterpret_cast<uint4*>(
        h + ((size_t)b * Cm_ + o) * HW_ + hw0 + tn * 8);
    *dst = *reinterpret_cast<const uint4*>(pk);
  }
}

// ---------------- Kernel 2a: softmax weights -> vt[b][hw][k], k=n*128+c -----
// grid: (W/8, H, B), block 256. Thread owns ONE channel c = t&127 and
// 4 pixels px = (t>>7) + {0,2,4,6}; Wg' loaded once per thread; all
// register arrays statically indexed.
__global__ __launch_bounds__(256) void k2a_weights(
    const unsigned short* __restrict__ h,
    const float* __restrict__ Wgf, const float* __restrict__ bgf,
    unsigned short* __restrict__ vt) {
  __shared__ unsigned short ht[Cm_ * 30];     // [c][r(3)][xx(10)] bf16
  __shared__ unsigned short vbuf[8][CN_];     // [px][k = n*128+c] bf16

  const int b  = blockIdx.z;
  const int y  = blockIdx.y;
  const int x0 = blockIdx.x * 8;
  const int t  = threadIdx.x;

  // stage h halo tile (rows y-1..y+1, cols x0-1..x0+8), zero-padded
  for (int idx = t; idx < Cm_ * 30; idx += 256) {
    int c   = idx / 30;
    int rem = idx - c * 30;
    int r   = rem / 10;
    int xx  = rem - r * 10;
    int gy  = y + r - 1;
    int gx  = x0 + xx - 1;
    unsigned short val = 0;
    if ((unsigned)gy < (unsigned)H_ && (unsigned)gx < (unsigned)W_)
      val = h[((size_t)b * Cm_ + c) * HW_ + gy * W_ + gx];
    ht[idx] = val;
  }
  __syncthreads();

  const int c  = t & 127;
  const int p0 = t >> 7;          // 0 or 1 (wave-uniform)

  // patches for 4 pixels, statically indexed: p[j][r*3+cc]
  float p[4][9];
  {
    float f[3][10];
#pragma unroll
    for (int r = 0; r < 3; ++r) {
      const unsigned int* src =
          reinterpret_cast<const unsigned int*>(&ht[c * 30 + r * 10]);
#pragma unroll
      for (int u = 0; u < 5; ++u) {
        unsigned int d = src[u];
        f[r][2 * u]     = bf2f((unsigned short)(d & 0xffffu));
        f[r][2 * u + 1] = bf2f((unsigned short)(d >> 16));
      }
    }
#pragma unroll
    for (int j = 0; j < 4; ++j)
#pragma unroll
      for (int r = 0; r < 3; ++r)
#pragma unroll
        for (int cc = 0; cc < 3; ++cc)
          p[j][r * 3 + cc] = p0 ? f[r][2 * j + 1 + cc] : f[r][2 * j + cc];
  }

  // 9->9 mixing with BN-folded weights (loaded once per thread)
  float wv[9][4];
#pragma unroll
  for (int n = 0; n < 9; ++n) {
    float bgv = bgf[c * 9 + n];
    float wg[9];
#pragma unroll
    for (int i = 0; i < 9; ++i) wg[i] = Wgf[c * 81 + n * 9 + i];
#pragma unroll
    for (int j = 0; j < 4; ++j) {
      float a = bgv;
#pragma unroll
      for (int i = 0; i < 9; ++i) a = fmaf(wg[i], p[j][i], a);
      wv[n][j] = a;
    }
  }

  // softmax over n, weighted patches -> vbuf (K-permuted, lane-coalesced)
#pragma unroll
  for (int j = 0; j < 4; ++j) {
    int px = p0 + 2 * j;
    float mx = wv[0][j];
#pragma unroll
    for (int n = 1; n < 9; ++n) mx = fmaxf(mx, wv[n][j]);
    float e[9], sum = 0.f;
#pragma unroll
    for (int n = 0; n < 9; ++n) { e[n] = __expf(wv[n][j] - mx); sum += e[n]; }
    float inv = 1.f / sum;
#pragma unroll
    for (int n = 0; n < 9; ++n)
      vbuf[px][n * 128 + c] = f2bf(p[j][n] * e[n] * inv);
  }
  __syncthreads();

  // write-out: coalesced 16-B chunks
  for (int idx = t; idx < 8 * (CN_ / 8); idx += 256) {   // 1152 chunks
    int px  = idx / 144;
    int off = idx - px * 144;
    const uint4* src = reinterpret_cast<const uint4*>(&vbuf[px][off * 8]);
    int hw = y * W_ + x0 + px;
    uint4* dst = reinterpret_cast<uint4*>(vt + ((size_t)b * HW_ + hw) * CN_ + off * 8);
    *dst = *src;
  }
}

// ---------------- Kernel 2b: out = x + relu(BN2(Wcb @ vt + bc)) via MFMA ----
// grid: (HW/64, 2, B), block 256 (4 waves). Block tile M=128 x N=64;
// wave w owns m-frags {2w, 2w+1} x 4 n-frags. No LDS; 2-deep reg pipeline.
__global__ __launch_bounds__(256) void k2b_gemm(
    const unsigned short* __restrict__ Wcb, const unsigned short* __restrict__ vt,
    const float* __restrict__ A2, const float* __restrict__ B2,
    const float* __restrict__ x, float* __restrict__ out) {
  const int b   = blockIdx.z;
  const int my  = blockIdx.y;          // m half: 0..1
  const int n0  = blockIdx.x * 64;
  const int t   = threadIdx.x;
  const int w   = __builtin_amdgcn_readfirstlane(t >> 6);
  const int l   = t & 63;
  const int l15 = l & 15;
  const int lhi = l >> 4;

  const unsigned short* aptr = Wcb + (size_t)(my * 128 + w * 32 + l15) * CN_ + 8 * lhi;
  const unsigned short* bptr = vt + ((size_t)b * HW_ + n0 + l15) * CN_ + 8 * lhi;

  f32x4 acc[2][4];
#pragma unroll
  for (int i = 0; i < 2; ++i)
#pragma unroll
    for (int nf = 0; nf < 4; ++nf) acc[i][nf] = (f32x4)0.f;

  bf16x8 a0[2], b0v[4], a1[2], b1v[4];

#define LOADA(DST, KK)                                                        \
  _Pragma("unroll") for (int i = 0; i < 2; ++i)                               \
      DST[i] = *reinterpret_cast<const bf16x8*>(aptr + i * 16 * CN_ + (KK));
#define LOADB(DST, KK)                                                        \
  _Pragma("unroll") for (int nf = 0; nf < 4; ++nf)                            \
      DST[nf] = *reinterpret_cast<const bf16x8*>(bptr + nf * 16 * CN_ + (KK));
#define MF(AS, BS)                                                            \
  _Pragma("unroll") for (int i = 0; i < 2; ++i)                               \
      _Pragma("unroll") for (int nf = 0; nf < 4; ++nf)                        \
          acc[i][nf] = __builtin_amdgcn_mfma_f32_16x16x32_bf16(               \
              AS[i], BS[nf], acc[i][nf], 0, 0, 0);

  LOADA(a0, 0) LOADB(b0v, 0)
  for (int kb = 0; kb < 17; ++kb) {
    const int kk = kb * 64;
    LOADA(a1, kk + 32) LOADB(b1v, kk + 32)
    MF(a0, b0v)
    LOADA(a0, kk + 64) LOADB(b0v, kk + 64)
    MF(a1, b1v)
  }
  LOADA(a1, 1120) LOADB(b1v, 1120)
  MF(a0, b0v)   // kk = 1088
  MF(a1, b1v)   // kk = 1120

  // epilogue: BN2 + ReLU + residual
#pragma unroll
  for (int i = 0; i < 2; ++i) {
#pragma unroll
    for (int r = 0; r < 4; ++r) {
      int o = my * 128 + w * 32 + i * 16 + lhi * 4 + r;
      float sA = A2[o], sB = B2[o];
#pragma unroll
      for (int nf = 0; nf < 4; ++nf) {
        float val = fmaf(acc[i][nf][r], sA, sB);
        val = fmaxf(val, 0.f);
        size_t idx = ((size_t)b * C2_ + o) * HW_ + n0 + nf * 16 + l15;
        out[idx] = x[idx] + val;
      }
    }
  }
#undef LOADA
#undef LOADB
#undef MF
}

extern "C" void kernel_launch(void* const* d_in, const int* in_sizes, int n_in,
                              void* d_out, int out_size, void* d_ws, size_t ws_size,
                              hipStream_t stream) {
  (void)in_sizes; (void)n_in; (void)out_size; (void)ws_size;
  const float* x   = (const float*)d_in[0];
  const float* W1  = (const float*)d_in[1];
  const float* g1  = (const float*)d_in[2];
  const float* b1  = (const float*)d_in[3];
  const float* m1  = (const float*)d_in[4];
  const float* v1  = (const float*)d_in[5];
  const float* Wg  = (const float*)d_in[6];
  const float* bg  = (const float*)d_in[7];
  const float* gg  = (const float*)d_in[8];
  const float* bgw = (const float*)d_in[9];
  const float* mg  = (const float*)d_in[10];
  const float* vg  = (const float*)d_in[11];
  const float* Wc  = (const float*)d_in[12];
  const float* bc  = (const float*)d_in[13];
  const float* g2  = (const float*)d_in[14];
  const float* b2  = (const float*)d_in[15];
  const float* m2  = (const float*)d_in[16];
  const float* v2  = (const float*)d_in[17];
  float* outp = (float*)d_out;

  // workspace layout (bytes):
  //   h   : bf16 [8][128][6400]      13,107,200
  //   vt  : bf16 [8][6400][1152]    117,964,800
  //   Wcb : bf16 [256][1152]            589,824 (K-permuted)
  //   Wgf : f32  [128][81]               41,472 (BN-folded)
  //   bgf : f32  [128][9]                 4,608
  //   A2,B2: f32 [256] each               2,048
  char* ws = (char*)d_ws;
  unsigned short* h   = (unsigned short*)ws;
  unsigned short* vt  = (unsigned short*)(ws + 13107200);
  unsigned short* Wcb = (unsigned short*)(ws + 131072000);
  float*          Wgf = (float*)(ws + 131072000 + 589824);
  float*          bgf = (float*)(ws + 131072000 + 589824 + 41472);
  float*          A2  = (float*)(ws + 131072000 + 589824 + 41472 + 4608);
  float*          B2  = A2 + C2_;

  k0_prep<<<dim3((C2_ * CN_ + 255) / 256), 256, 0, stream>>>(
      Wc, bc, g2, b2, m2, v2, Wg, bg, gg, bgw, mg, vg, Wcb, A2, B2, Wgf, bgf);

  dim3 grid1(HW_ / 128, B_);
  k1_cv1<<<grid1, 256, 0, stream>>>(x, W1, g1, b1, m1, v1, h);

  dim3 grid2a(W_ / 8, H_, B_);
  k2a_weights<<<grid2a, 256, 0, stream>>>(h, Wgf, bgf, vt);

  dim3 grid2b(HW_ / 64, 2, B_);
  k2b_gemm<<<grid2b, 256, 0, stream>>>(Wcb, vt, A2, B2, x, outp);
}

// Round 10
// 215.853 us; speedup vs baseline: 3.5916x; 1.5054x over previous
//
#include <hip/hip_runtime.h>
#include <hip/hip_bf16.h>

#define B_   8
#define C1_  256
#define C2_  256
#define Cm_  128    // C_ = C2/2
#define H_   80
#define W_   80
#define HW_  6400
#define CN_  1152   // C_ * 9
#define EPS_ 1e-5f

typedef __attribute__((ext_vector_type(8))) short bf16x8;
typedef __attribute__((ext_vector_type(4))) float f32x4;

__device__ inline unsigned short f2bf(float f) {
  union { float f; unsigned int u; } v; v.f = f;
  unsigned int u = v.u;
  unsigned int r = (u + 0x7FFFu + ((u >> 16) & 1u)) >> 16;
  return (unsigned short)r;
}
__device__ inline float bf2f(unsigned short s) {
  union { unsigned int u; float f; } v; v.u = ((unsigned int)s) << 16;
  return v.f;
}

__device__ __forceinline__ void gload16(const void* g, void* l) {
  __builtin_amdgcn_global_load_lds(
      (const __attribute__((address_space(1))) void*)g,
      (__attribute__((address_space(3))) void*)l, 16, 0, 0);
}

// ---- Kernel 0: prep — Wc->bf16 K-permuted, BN-folded Wg', BN2 scale/shift --
__global__ __launch_bounds__(256) void k0_prep(
    const float* __restrict__ Wc, const float* __restrict__ bc,
    const float* __restrict__ g2, const float* __restrict__ b2,
    const float* __restrict__ m2, const float* __restrict__ v2,
    const float* __restrict__ Wg, const float* __restrict__ bg,
    const float* __restrict__ gg, const float* __restrict__ bgw,
    const float* __restrict__ mg, const float* __restrict__ vg,
    unsigned short* __restrict__ Wcb, float* __restrict__ A2,
    float* __restrict__ B2, float* __restrict__ Wgf,
    float* __restrict__ bgf) {
  int idx = blockIdx.x * 256 + threadIdx.x;
  if (idx < C2_ * CN_) {
    int o = idx / CN_;
    int r = idx - o * CN_;
    int n = r >> 7;          // 0..8
    int c = r & 127;         // 0..127
    Wcb[idx] = f2bf(Wc[o * CN_ + c * 9 + n]);
  }
  if (idx < Cm_ * 81) {
    int c  = idx / 81;
    int oi = idx - c * 81;
    int o  = oi / 9;
    float sg = gg[c * 9 + o] * rsqrtf(vg[c * 9 + o] + EPS_);
    Wgf[idx] = Wg[idx] * sg;
  }
  if (idx < Cm_ * 9) {
    float sg = gg[idx] * rsqrtf(vg[idx] + EPS_);
    bgf[idx] = (bg[idx] - mg[idx]) * sg + bgw[idx];
  }
  if (idx < C2_) {
    float s = g2[idx] * rsqrtf(v2[idx] + EPS_);
    A2[idx] = s;
    B2[idx] = (bc[idx] - m2[idx]) * s + b2[idx];
  }
}

// ---------------- Kernel 1: h = SiLU(BN1(W1 @ x)), bf16 out -----------------
__global__ __launch_bounds__(256) void k1_cv1(
    const float* __restrict__ x, const float* __restrict__ W1,
    const float* __restrict__ g1, const float* __restrict__ b1,
    const float* __restrict__ m1, const float* __restrict__ v1,
    unsigned short* __restrict__ h) {
  __shared__ float ws[16][128];
  __shared__ float xs[16][128];
  const int b   = blockIdx.y;
  const int hw0 = blockIdx.x * 128;
  const int t   = threadIdx.x;
  const int tn  = t & 15;
  const int tm  = t >> 4;

  float acc[8][8];
#pragma unroll
  for (int i = 0; i < 8; ++i)
#pragma unroll
    for (int j = 0; j < 8; ++j) acc[i][j] = 0.f;

  const int m_l = t & 127;
  for (int c0 = 0; c0 < C1_; c0 += 16) {
#pragma unroll
    for (int i = 0; i < 8; ++i) {
      int idx = t + i * 256;
      int kk = idx >> 7;
      ws[kk][m_l] = W1[m_l * C1_ + c0 + kk];
    }
#pragma unroll
    for (int i = 0; i < 8; ++i) {
      int idx = t + i * 256;
      int kk = idx >> 7;
      xs[kk][m_l] = x[((size_t)b * C1_ + c0 + kk) * HW_ + hw0 + m_l];
    }
    __syncthreads();
#pragma unroll
    for (int kk = 0; kk < 16; ++kk) {
      float av[8], bv[8];
      *reinterpret_cast<float4*>(&av[0]) = *reinterpret_cast<const float4*>(&ws[kk][tm * 8]);
      *reinterpret_cast<float4*>(&av[4]) = *reinterpret_cast<const float4*>(&ws[kk][tm * 8 + 4]);
      *reinterpret_cast<float4*>(&bv[0]) = *reinterpret_cast<const float4*>(&xs[kk][tn * 8]);
      *reinterpret_cast<float4*>(&bv[4]) = *reinterpret_cast<const float4*>(&xs[kk][tn * 8 + 4]);
#pragma unroll
      for (int i = 0; i < 8; ++i)
#pragma unroll
        for (int j = 0; j < 8; ++j)
          acc[i][j] = fmaf(av[i], bv[j], acc[i][j]);
    }
    __syncthreads();
  }
#pragma unroll
  for (int i = 0; i < 8; ++i) {
    int o = tm * 8 + i;
    float s  = g1[o] * rsqrtf(v1[o] + EPS_);
    float sh = b1[o] - m1[o] * s;
    unsigned short pk[8];
#pragma unroll
    for (int j = 0; j < 8; ++j) {
      float val = fmaf(acc[i][j], s, sh);
      float sig = 1.f / (1.f + __expf(-val));
      pk[j] = f2bf(val * sig);
    }
    uint4* dst = reinterpret_cast<uint4*>(
        h + ((size_t)b * Cm_ + o) * HW_ + hw0 + tn * 8);
    *dst = *reinterpret_cast<const uint4*>(pk);
  }
}

// ---------------- Kernel 2a: softmax weights -> vt[b][hw][k], k=n*128+c -----
__global__ __launch_bounds__(256) void k2a_weights(
    const unsigned short* __restrict__ h,
    const float* __restrict__ Wgf, const float* __restrict__ bgf,
    unsigned short* __restrict__ vt) {
  __shared__ unsigned short ht[Cm_ * 30];     // [c][r(3)][xx(10)] bf16
  __shared__ unsigned short vbuf[8][CN_];     // [px][k = n*128+c] bf16

  const int b  = blockIdx.z;
  const int y  = blockIdx.y;
  const int x0 = blockIdx.x * 8;
  const int t  = threadIdx.x;

  for (int idx = t; idx < Cm_ * 30; idx += 256) {
    int c   = idx / 30;
    int rem = idx - c * 30;
    int r   = rem / 10;
    int xx  = rem - r * 10;
    int gy  = y + r - 1;
    int gx  = x0 + xx - 1;
    unsigned short val = 0;
    if ((unsigned)gy < (unsigned)H_ && (unsigned)gx < (unsigned)W_)
      val = h[((size_t)b * Cm_ + c) * HW_ + gy * W_ + gx];
    ht[idx] = val;
  }
  __syncthreads();

  const int c  = t & 127;
  const int p0 = t >> 7;          // 0 or 1 (wave-uniform)

  float p[4][9];
  {
    float f[3][10];
#pragma unroll
    for (int r = 0; r < 3; ++r) {
      const unsigned int* src =
          reinterpret_cast<const unsigned int*>(&ht[c * 30 + r * 10]);
#pragma unroll
      for (int u = 0; u < 5; ++u) {
        unsigned int d = src[u];
        f[r][2 * u]     = bf2f((unsigned short)(d & 0xffffu));
        f[r][2 * u + 1] = bf2f((unsigned short)(d >> 16));
      }
    }
#pragma unroll
    for (int j = 0; j < 4; ++j)
#pragma unroll
      for (int r = 0; r < 3; ++r)
#pragma unroll
        for (int cc = 0; cc < 3; ++cc)
          p[j][r * 3 + cc] = p0 ? f[r][2 * j + 1 + cc] : f[r][2 * j + cc];
  }

  float wv[9][4];
#pragma unroll
  for (int n = 0; n < 9; ++n) {
    float bgv = bgf[c * 9 + n];
    float wg[9];
#pragma unroll
    for (int i = 0; i < 9; ++i) wg[i] = Wgf[c * 81 + n * 9 + i];
#pragma unroll
    for (int j = 0; j < 4; ++j) {
      float a = bgv;
#pragma unroll
      for (int i = 0; i < 9; ++i) a = fmaf(wg[i], p[j][i], a);
      wv[n][j] = a;
    }
  }

#pragma unroll
  for (int j = 0; j < 4; ++j) {
    int px = p0 + 2 * j;
    float mx = wv[0][j];
#pragma unroll
    for (int n = 1; n < 9; ++n) mx = fmaxf(mx, wv[n][j]);
    float e[9], sum = 0.f;
#pragma unroll
    for (int n = 0; n < 9; ++n) { e[n] = __expf(wv[n][j] - mx); sum += e[n]; }
    float inv = 1.f / sum;
#pragma unroll
    for (int n = 0; n < 9; ++n)
      vbuf[px][n * 128 + c] = f2bf(p[j][n] * e[n] * inv);
  }
  __syncthreads();

  for (int idx = t; idx < 8 * (CN_ / 8); idx += 256) {   // 1152 chunks
    int px  = idx / 144;
    int off = idx - px * 144;
    const uint4* src = reinterpret_cast<const uint4*>(&vbuf[px][off * 8]);
    int hw = y * W_ + x0 + px;
    uint4* dst = reinterpret_cast<uint4*>(vt + ((size_t)b * HW_ + hw) * CN_ + off * 8);
    *dst = *src;
  }
}

// ---------------- Kernel 2b v3: LDS-staged 2-phase pipelined MFMA GEMM ------
// BM=256 (full M: vt read once), BN=64, BK=64. 512 thr = 8 waves (4M x 2N).
// Both operands via global_load_lds into double-buffered, XOR-swizzled LDS.
// grid: (HW/64, B).
__global__ __launch_bounds__(512, 4) void k2b_gemm(
    const unsigned short* __restrict__ Wcb, const unsigned short* __restrict__ vt,
    const float* __restrict__ A2, const float* __restrict__ B2,
    const float* __restrict__ x, float* __restrict__ out) {
  __shared__ alignas(16) unsigned short Ash[2][256 * 64];  // 32 KB each
  __shared__ alignas(16) unsigned short Bsh[2][64 * 64];   //  8 KB each

  const int b   = blockIdx.y;
  const int n0  = blockIdx.x * 64;
  const int t   = threadIdx.x;
  const int w   = __builtin_amdgcn_readfirstlane(t >> 6);
  const int l   = t & 63;
  const int l15 = l & 15;
  const int lhi = l >> 4;
  const int mw  = w >> 1;        // 0..3
  const int nw  = w & 1;         // 0..1

  // staging source byte offsets (inverse-swizzled), constant per thread
  const char* WcbB = (const char*)Wcb;
  const char* vtB  = (const char*)vt;
  int  aoffs[4], aldsb[4];
#pragma unroll
  for (int j = 0; j < 4; ++j) {
    int L16  = (w * 4 + j) * 64 + l;     // 16B-chunk index 0..2047
    int row  = L16 >> 3;                 // 0..255
    int colb = (L16 & 7) * 16;
    aoffs[j] = row * (CN_ * 2) + (colb ^ ((row & 7) << 4));
    aldsb[j] = L16 * 16;
  }
  const int bpx  = t >> 3;               // 0..63
  const long boff = (long)((size_t)(b * HW_ + n0 + bpx) * CN_) * 2 +
                    (((t & 7) * 16) ^ ((bpx & 7) << 4));
  const int bldsb = t * 16;

#define STAGE(BUF, TT) do {                                                    \
    _Pragma("unroll") for (int j = 0; j < 4; ++j)                              \
      gload16(WcbB + aoffs[j] + (TT) * 128, (char*)&Ash[BUF][0] + aldsb[j]);   \
    gload16(vtB + boff + (TT) * 128, (char*)&Bsh[BUF][0] + bldsb);             \
  } while (0)

  f32x4 acc[4][2];
#pragma unroll
  for (int i = 0; i < 4; ++i)
#pragma unroll
    for (int nf = 0; nf < 2; ++nf) acc[i][nf] = (f32x4)0.f;

  const int swzs = (l15 & 7) << 3;   // read swizzle (shorts); row&7 == l15&7
  const int lhi8 = lhi * 8;

  STAGE(0, 0);
  __syncthreads();

  int cur = 0;
  for (int tt = 0; tt < 18; ++tt) {
    if (tt < 17) STAGE(cur ^ 1, tt + 1);
    const unsigned short* Ab = &Ash[cur][0];
    const unsigned short* Bb = &Bsh[cur][0];
#pragma unroll
    for (int ks = 0; ks < 2; ++ks) {
      bf16x8 av[4], bv[2];
#pragma unroll
      for (int mf = 0; mf < 4; ++mf) {
        int row = mw * 64 + mf * 16 + l15;
        av[mf] = *reinterpret_cast<const bf16x8*>(
            Ab + row * 64 + (((ks << 5) + lhi8) ^ swzs));
      }
#pragma unroll
      for (int nf = 0; nf < 2; ++nf) {
        int row = nw * 32 + nf * 16 + l15;
        bv[nf] = *reinterpret_cast<const bf16x8*>(
            Bb + row * 64 + (((ks << 5) + lhi8) ^ swzs));
      }
#pragma unroll
      for (int mf = 0; mf < 4; ++mf)
#pragma unroll
        for (int nf = 0; nf < 2; ++nf)
          acc[mf][nf] = __builtin_amdgcn_mfma_f32_16x16x32_bf16(
              av[mf], bv[nf], acc[mf][nf], 0, 0, 0);
    }
    __syncthreads();   // drains vmcnt (next buf staged) + lgkm; protects overwrite
    cur ^= 1;
  }
#undef STAGE

  // epilogue: BN2 + ReLU + residual
#pragma unroll
  for (int mf = 0; mf < 4; ++mf) {
#pragma unroll
    for (int r = 0; r < 4; ++r) {
      int o = mw * 64 + mf * 16 + lhi * 4 + r;
      float sA = A2[o], sB = B2[o];
#pragma unroll
      for (int nf = 0; nf < 2; ++nf) {
        float val = fmaf(acc[mf][nf][r], sA, sB);
        val = fmaxf(val, 0.f);
        size_t idx = ((size_t)b * C2_ + o) * HW_ + n0 + nw * 32 + nf * 16 + l15;
        out[idx] = x[idx] + val;
      }
    }
  }
}

extern "C" void kernel_launch(void* const* d_in, const int* in_sizes, int n_in,
                              void* d_out, int out_size, void* d_ws, size_t ws_size,
                              hipStream_t stream) {
  (void)in_sizes; (void)n_in; (void)out_size; (void)ws_size;
  const float* x   = (const float*)d_in[0];
  const float* W1  = (const float*)d_in[1];
  const float* g1  = (const float*)d_in[2];
  const float* b1  = (const float*)d_in[3];
  const float* m1  = (const float*)d_in[4];
  const float* v1  = (const float*)d_in[5];
  const float* Wg  = (const float*)d_in[6];
  const float* bg  = (const float*)d_in[7];
  const float* gg  = (const float*)d_in[8];
  const float* bgw = (const float*)d_in[9];
  const float* mg  = (const float*)d_in[10];
  const float* vg  = (const float*)d_in[11];
  const float* Wc  = (const float*)d_in[12];
  const float* bc  = (const float*)d_in[13];
  const float* g2  = (const float*)d_in[14];
  const float* b2  = (const float*)d_in[15];
  const float* m2  = (const float*)d_in[16];
  const float* v2  = (const float*)d_in[17];
  float* outp = (float*)d_out;

  // workspace layout (bytes):
  //   h   : bf16 [8][128][6400]      13,107,200
  //   vt  : bf16 [8][6400][1152]    117,964,800
  //   Wcb : bf16 [256][1152]            589,824 (K-permuted)
  //   Wgf : f32  [128][81]               41,472 (BN-folded)
  //   bgf : f32  [128][9]                 4,608
  //   A2,B2: f32 [256] each               2,048
  char* ws = (char*)d_ws;
  unsigned short* h   = (unsigned short*)ws;
  unsigned short* vt  = (unsigned short*)(ws + 13107200);
  unsigned short* Wcb = (unsigned short*)(ws + 131072000);
  float*          Wgf = (float*)(ws + 131072000 + 589824);
  float*          bgf = (float*)(ws + 131072000 + 589824 + 41472);
  float*          A2  = (float*)(ws + 131072000 + 589824 + 41472 + 4608);
  float*          B2  = A2 + C2_;

  k0_prep<<<dim3((C2_ * CN_ + 255) / 256), 256, 0, stream>>>(
      Wc, bc, g2, b2, m2, v2, Wg, bg, gg, bgw, mg, vg, Wcb, A2, B2, Wgf, bgf);

  dim3 grid1(HW_ / 128, B_);
  k1_cv1<<<grid1, 256, 0, stream>>>(x, W1, g1, b1, m1, v1, h);

  dim3 grid2a(W_ / 8, H_, B_);
  k2a_weights<<<grid2a, 256, 0, stream>>>(h, Wgf, bgf, vt);

  dim3 grid2b(HW_ / 64, B_);
  k2b_gemm<<<grid2b, 512, 0, stream>>>(Wcb, vt, A2, B2, x, outp);
}

// Round 12
// 152.664 us; speedup vs baseline: 5.0781x; 1.4139x over previous
//
#include <hip/hip_runtime.h>
#include <hip/hip_bf16.h>

#define B_   8
#define C1_  256
#define C2_  256
#define Cm_  128    // C_ = C2/2
#define H_   80
#define W_   80
#define HW_  6400
#define CN_  1152   // C_ * 9
#define EPS_ 1e-5f

typedef __attribute__((ext_vector_type(8))) short bf16x8;
typedef __attribute__((ext_vector_type(4))) float f32x4;

__device__ inline unsigned short f2bf(float f) {
  union { float f; unsigned int u; } v; v.f = f;
  unsigned int u = v.u;
  unsigned int r = (u + 0x7FFFu + ((u >> 16) & 1u)) >> 16;
  return (unsigned short)r;
}
__device__ inline float bf2f(unsigned short s) {
  union { unsigned int u; float f; } v; v.u = ((unsigned int)s) << 16;
  return v.f;
}

__device__ __forceinline__ void gload16(const void* g, void* l) {
  __builtin_amdgcn_global_load_lds(
      (const __attribute__((address_space(1))) void*)g,
      (__attribute__((address_space(3))) void*)l, 16, 0, 0);
}

// ---- Kernel 0: prep --------------------------------------------------------
// Wcb[o][n*128+c]=Wc[o][c*9+n]; Wgt[oi][c]=Wg*sg (transposed, coalesced);
// bgt[n][c]=folded bias; W1b = bf16(W1); A2/B2 = BN2 scale/shift.
__global__ __launch_bounds__(256) void k0_prep(
    const float* __restrict__ Wc, const float* __restrict__ bc,
    const float* __restrict__ g2, const float* __restrict__ b2,
    const float* __restrict__ m2, const float* __restrict__ v2,
    const float* __restrict__ Wg, const float* __restrict__ bg,
    const float* __restrict__ gg, const float* __restrict__ bgw,
    const float* __restrict__ mg, const float* __restrict__ vg,
    const float* __restrict__ W1,
    unsigned short* __restrict__ Wcb, float* __restrict__ A2,
    float* __restrict__ B2, float* __restrict__ Wgt,
    float* __restrict__ bgt, unsigned short* __restrict__ W1b) {
  int idx = blockIdx.x * 256 + threadIdx.x;
  if (idx < C2_ * CN_) {
    int o = idx / CN_;
    int r = idx - o * CN_;
    int n = r >> 7;          // 0..8
    int c = r & 127;         // 0..127
    Wcb[idx] = f2bf(Wc[o * CN_ + c * 9 + n]);
  }
  if (idx < Cm_ * 81) {
    int c  = idx / 81;
    int oi = idx - c * 81;
    int n  = oi / 9;
    float sg = gg[c * 9 + n] * rsqrtf(vg[c * 9 + n] + EPS_);
    Wgt[oi * 128 + c] = Wg[idx] * sg;
  }
  if (idx < Cm_ * 9) {
    int c = idx / 9;
    int n = idx - c * 9;
    float sg = gg[idx] * rsqrtf(vg[idx] + EPS_);
    bgt[n * 128 + c] = (bg[idx] - mg[idx]) * sg + bgw[idx];
  }
  if (idx < Cm_ * C1_) W1b[idx] = f2bf(W1[idx]);
  if (idx < C2_) {
    float s = g2[idx] * rsqrtf(v2[idx] + EPS_);
    A2[idx] = s;
    B2[idx] = (bc[idx] - m2[idx]) * s + b2[idx];
  }
}

// ---------------- Kernel 1 v2: h = SiLU(BN1(W1b @ x)) via MFMA --------------
// BM=128 (full M), BN=64, BK=64, 4 K-chunks. 256 thr = 4 waves (wave = 32 M).
// A: bf16 W1b via global_load_lds (inverse-swizzled source, linear LDS).
// B: x f32 -> cvt bf16 -> swizzled transposed ds_write (reg-staged).
// grid: (HW/64, B).
__global__ __launch_bounds__(256) void k1_cv1(
    const float* __restrict__ x, const unsigned short* __restrict__ W1b,
    const float* __restrict__ g1, const float* __restrict__ b1,
    const float* __restrict__ m1, const float* __restrict__ v1,
    unsigned short* __restrict__ h) {
  __shared__ alignas(16) unsigned short Ash[2][128 * 64];  // 16 KB each
  __shared__ alignas(16) unsigned short Bsh[2][64 * 64];   //  8 KB each

  const int b   = blockIdx.y;
  const int hw0 = blockIdx.x * 64;
  const int t   = threadIdx.x;
  const int w   = __builtin_amdgcn_readfirstlane(t >> 6);
  const int l15 = t & 15;
  const int lhi = (t & 63) >> 4;

  // A staging: 1024 16B-chunks, 4 per thread, inverse-swizzled source
  const char* W1B = (const char*)W1b;
  int aoffs[4], aldsb[4];
#pragma unroll
  for (int j = 0; j < 4; ++j) {
    int L16  = j * 256 + t;
    int row  = L16 >> 3;
    int colb = (L16 & 7) * 16;
    aoffs[j] = row * (C1_ * 2) + (colb ^ ((row & 7) << 4));
    aldsb[j] = L16 * 16;
  }
  // B reg-stage mapping: lane owns channel c_l, px block = w*16..+15
  const int c_l = t & 63;
  const int px0 = (t >> 6) * 16;

#define STAGEA(BUF, KC)                                                        \
  _Pragma("unroll") for (int j = 0; j < 4; ++j)                                \
      gload16(W1B + aoffs[j] + (KC) * 128, (char*)&Ash[BUF][0] + aldsb[j]);
#define LOADB(KC)                                                              \
  _Pragma("unroll") for (int u = 0; u < 4; ++u)                                \
      xv[u] = *reinterpret_cast<const float4*>(                                \
          x + ((size_t)(b * C1_ + (KC) * 64 + c_l)) * HW_ + hw0 + px0 + u * 4);
#define WRITEB(BUF)                                                            \
  _Pragma("unroll") for (int u = 0; u < 4; ++u)                                \
    _Pragma("unroll") for (int e = 0; e < 4; ++e) {                            \
      int px = px0 + u * 4 + e;                                                \
      float vv = (e == 0) ? xv[u].x : (e == 1) ? xv[u].y                       \
               : (e == 2) ? xv[u].z : xv[u].w;                                 \
      Bsh[BUF][px * 64 + (c_l ^ (((u * 4 + e) & 7) << 3))] = f2bf(vv);         \
    }

  f32x4 acc[2][4];
#pragma unroll
  for (int i = 0; i < 2; ++i)
#pragma unroll
    for (int nf = 0; nf < 4; ++nf) acc[i][nf] = (f32x4)0.f;

  const int swzs = (l15 & 7) << 3;
  const int lhi8 = lhi * 8;

  float4 xv[4];
  STAGEA(0, 0);
  LOADB(0);
  WRITEB(0);
  __syncthreads();

  int cur = 0;
  for (int kc = 0; kc < 4; ++kc) {
    if (kc < 3) {
      STAGEA(cur ^ 1, kc + 1);
      LOADB(kc + 1);
    }
    const unsigned short* Ab = &Ash[cur][0];
    const unsigned short* Bb = &Bsh[cur][0];
#pragma unroll
    for (int ks = 0; ks < 2; ++ks) {
      bf16x8 av[2], bv[4];
#pragma unroll
      for (int mf = 0; mf < 2; ++mf) {
        int row = w * 32 + mf * 16 + l15;
        av[mf] = *reinterpret_cast<const bf16x8*>(
            Ab + row * 64 + (((ks << 5) + lhi8) ^ swzs));
      }
#pragma unroll
      for (int nf = 0; nf < 4; ++nf) {
        int row = nf * 16 + l15;
        bv[nf] = *reinterpret_cast<const bf16x8*>(
            Bb + row * 64 + (((ks << 5) + lhi8) ^ swzs));
      }
#pragma unroll
      for (int mf = 0; mf < 2; ++mf)
#pragma unroll
        for (int nf = 0; nf < 4; ++nf)
          acc[mf][nf] = __builtin_amdgcn_mfma_f32_16x16x32_bf16(
              av[mf], bv[nf], acc[mf][nf], 0, 0, 0);
    }
    if (kc < 3) WRITEB(cur ^ 1);
    __syncthreads();
    cur ^= 1;
  }
#undef STAGEA
#undef LOADB
#undef WRITEB

  // epilogue: BN1 + SiLU -> h bf16
#pragma unroll
  for (int mf = 0; mf < 2; ++mf) {
#pragma unroll
    for (int r = 0; r < 4; ++r) {
      int o = w * 32 + mf * 16 + lhi * 4 + r;
      float s  = g1[o] * rsqrtf(v1[o] + EPS_);
      float sh = b1[o] - m1[o] * s;
#pragma unroll
      for (int nf = 0; nf < 4; ++nf) {
        float val = fmaf(acc[mf][nf][r], s, sh);
        float sig = 1.f / (1.f + __expf(-val));
        h[((size_t)b * Cm_ + o) * HW_ + hw0 + nf * 16 + l15] = f2bf(val * sig);
      }
    }
  }
}

// ---------------- Kernel 2a: softmax weights -> vt[b][hw][k], k=n*128+c -----
__global__ __launch_bounds__(256) void k2a_weights(
    const unsigned short* __restrict__ h,
    const float* __restrict__ Wgt, const float* __restrict__ bgt,
    unsigned short* __restrict__ vt) {
  __shared__ unsigned short ht[Cm_ * 30];     // [c][r(3)][xx(10)] bf16
  __shared__ unsigned short vbuf[8][CN_];     // [px][k = n*128+c] bf16

  const int b  = blockIdx.z;
  const int y  = blockIdx.y;
  const int x0 = blockIdx.x * 8;
  const int t  = threadIdx.x;

  for (int idx = t; idx < Cm_ * 30; idx += 256) {
    int c   = idx / 30;
    int rem = idx - c * 30;
    int r   = rem / 10;
    int xx  = rem - r * 10;
    int gy  = y + r - 1;
    int gx  = x0 + xx - 1;
    unsigned short val = 0;
    if ((unsigned)gy < (unsigned)H_ && (unsigned)gx < (unsigned)W_)
      val = h[((size_t)b * Cm_ + c) * HW_ + gy * W_ + gx];
    ht[idx] = val;
  }
  __syncthreads();

  const int c  = t & 127;
  const int p0 = t >> 7;          // 0 or 1 (wave-uniform)

  float p[4][9];
  {
    float f[3][10];
#pragma unroll
    for (int r = 0; r < 3; ++r) {
      const unsigned int* src =
          reinterpret_cast<const unsigned int*>(&ht[c * 30 + r * 10]);
#pragma unroll
      for (int u = 0; u < 5; ++u) {
        unsigned int d = src[u];
        f[r][2 * u]     = bf2f((unsigned short)(d & 0xffffu));
        f[r][2 * u + 1] = bf2f((unsigned short)(d >> 16));
      }
    }
#pragma unroll
    for (int j = 0; j < 4; ++j)
#pragma unroll
      for (int r = 0; r < 3; ++r)
#pragma unroll
        for (int cc = 0; cc < 3; ++cc)
          p[j][r * 3 + cc] = p0 ? f[r][2 * j + 1 + cc] : f[r][2 * j + cc];
  }

  // 9->9 mixing; weight loads now lane-coalesced (Wgt[oi][c], bgt[n][c])
  float wv[9][4];
#pragma unroll
  for (int n = 0; n < 9; ++n) {
    float bgv = bgt[n * 128 + c];
    float wg[9];
#pragma unroll
    for (int i = 0; i < 9; ++i) wg[i] = Wgt[(n * 9 + i) * 128 + c];
#pragma unroll
    for (int j = 0; j < 4; ++j) {
      float a = bgv;
#pragma unroll
      for (int i = 0; i < 9; ++i) a = fmaf(wg[i], p[j][i], a);
      wv[n][j] = a;
    }
  }

#pragma unroll
  for (int j = 0; j < 4; ++j) {
    int px = p0 + 2 * j;
    float mx = wv[0][j];
#pragma unroll
    for (int n = 1; n < 9; ++n) mx = fmaxf(mx, wv[n][j]);
    float e[9], sum = 0.f;
#pragma unroll
    for (int n = 0; n < 9; ++n) { e[n] = __expf(wv[n][j] - mx); sum += e[n]; }
    float inv = 1.f / sum;
#pragma unroll
    for (int n = 0; n < 9; ++n)
      vbuf[px][n * 128 + c] = f2bf(p[j][n] * e[n] * inv);
  }
  __syncthreads();

  for (int idx = t; idx < 8 * (CN_ / 8); idx += 256) {   // 1152 chunks
    int px  = idx / 144;
    int off = idx - px * 144;
    const uint4* src = reinterpret_cast<const uint4*>(&vbuf[px][off * 8]);
    int hw = y * W_ + x0 + px;
    uint4* dst = reinterpret_cast<uint4*>(vt + ((size_t)b * HW_ + hw) * CN_ + off * 8);
    *dst = *src;
  }
}

// ---------------- Kernel 2b v3: LDS-staged 2-phase pipelined MFMA GEMM ------
// BM=256 (full M: vt read once), BN=64, BK=64. 512 thr = 8 waves (4M x 2N).
__global__ __launch_bounds__(512, 4) void k2b_gemm(
    const unsigned short* __restrict__ Wcb, const unsigned short* __restrict__ vt,
    const float* __restrict__ A2, const float* __restrict__ B2,
    const float* __restrict__ x, float* __restrict__ out) {
  __shared__ alignas(16) unsigned short Ash[2][256 * 64];  // 32 KB each
  __shared__ alignas(16) unsigned short Bsh[2][64 * 64];   //  8 KB each

  const int b   = blockIdx.y;
  const int n0  = blockIdx.x * 64;
  const int t   = threadIdx.x;
  const int w   = __builtin_amdgcn_readfirstlane(t >> 6);
  const int l   = t & 63;
  const int l15 = l & 15;
  const int lhi = l >> 4;
  const int mw  = w >> 1;        // 0..3
  const int nw  = w & 1;         // 0..1

  const char* WcbB = (const char*)Wcb;
  const char* vtB  = (const char*)vt;
  int  aoffs[4], aldsb[4];
#pragma unroll
  for (int j = 0; j < 4; ++j) {
    int L16  = (w * 4 + j) * 64 + l;     // 16B-chunk index 0..2047
    int row  = L16 >> 3;                 // 0..255
    int colb = (L16 & 7) * 16;
    aoffs[j] = row * (CN_ * 2) + (colb ^ ((row & 7) << 4));
    aldsb[j] = L16 * 16;
  }
  const int bpx  = t >> 3;               // 0..63
  const long boff = (long)((size_t)(b * HW_ + n0 + bpx) * CN_) * 2 +
                    (((t & 7) * 16) ^ ((bpx & 7) << 4));
  const int bldsb = t * 16;

#define STAGE(BUF, TT) do {                                                    \
    _Pragma("unroll") for (int j = 0; j < 4; ++j)                              \
      gload16(WcbB + aoffs[j] + (TT) * 128, (char*)&Ash[BUF][0] + aldsb[j]);   \
    gload16(vtB + boff + (TT) * 128, (char*)&Bsh[BUF][0] + bldsb);             \
  } while (0)

  f32x4 acc[4][2];
#pragma unroll
  for (int i = 0; i < 4; ++i)
#pragma unroll
    for (int nf = 0; nf < 2; ++nf) acc[i][nf] = (f32x4)0.f;

  const int swzs = (l15 & 7) << 3;
  const int lhi8 = lhi * 8;

  STAGE(0, 0);
  __syncthreads();

  int cur = 0;
  for (int tt = 0; tt < 18; ++tt) {
    if (tt < 17) STAGE(cur ^ 1, tt + 1);
    const unsigned short* Ab = &Ash[cur][0];
    const unsigned short* Bb = &Bsh[cur][0];
#pragma unroll
    for (int ks = 0; ks < 2; ++ks) {
      bf16x8 av[4], bv[2];
#pragma unroll
      for (int mf = 0; mf < 4; ++mf) {
        int row = mw * 64 + mf * 16 + l15;
        av[mf] = *reinterpret_cast<const bf16x8*>(
            Ab + row * 64 + (((ks << 5) + lhi8) ^ swzs));
      }
#pragma unroll
      for (int nf = 0; nf < 2; ++nf) {
        int row = nw * 32 + nf * 16 + l15;
        bv[nf] = *reinterpret_cast<const bf16x8*>(
            Bb + row * 64 + (((ks << 5) + lhi8) ^ swzs));
      }
#pragma unroll
      for (int mf = 0; mf < 4; ++mf)
#pragma unroll
        for (int nf = 0; nf < 2; ++nf)
          acc[mf][nf] = __builtin_amdgcn_mfma_f32_16x16x32_bf16(
              av[mf], bv[nf], acc[mf][nf], 0, 0, 0);
    }
    __syncthreads();
    cur ^= 1;
  }
#undef STAGE

  // epilogue: BN2 + ReLU + residual
#pragma unroll
  for (int mf = 0; mf < 4; ++mf) {
#pragma unroll
    for (int r = 0; r < 4; ++r) {
      int o = mw * 64 + mf * 16 + lhi * 4 + r;
      float sA = A2[o], sB = B2[o];
#pragma unroll
      for (int nf = 0; nf < 2; ++nf) {
        float val = fmaf(acc[mf][nf][r], sA, sB);
        val = fmaxf(val, 0.f);
        size_t idx = ((size_t)b * C2_ + o) * HW_ + n0 + nw * 32 + nf * 16 + l15;
        out[idx] = x[idx] + val;
      }
    }
  }
}

extern "C" void kernel_launch(void* const* d_in, const int* in_sizes, int n_in,
                              void* d_out, int out_size, void* d_ws, size_t ws_size,
                              hipStream_t stream) {
  (void)in_sizes; (void)n_in; (void)out_size; (void)ws_size;
  const float* x   = (const float*)d_in[0];
  const float* W1  = (const float*)d_in[1];
  const float* g1  = (const float*)d_in[2];
  const float* b1  = (const float*)d_in[3];
  const float* m1  = (const float*)d_in[4];
  const float* v1  = (const float*)d_in[5];
  const float* Wg  = (const float*)d_in[6];
  const float* bg  = (const float*)d_in[7];
  const float* gg  = (const float*)d_in[8];
  const float* bgw = (const float*)d_in[9];
  const float* mg  = (const float*)d_in[10];
  const float* vg  = (const float*)d_in[11];
  const float* Wc  = (const float*)d_in[12];
  const float* bc  = (const float*)d_in[13];
  const float* g2  = (const float*)d_in[14];
  const float* b2  = (const float*)d_in[15];
  const float* m2  = (const float*)d_in[16];
  const float* v2  = (const float*)d_in[17];
  float* outp = (float*)d_out;

  // workspace layout (bytes):
  //   h   : bf16 [8][128][6400]      13,107,200   @ 0
  //   vt  : bf16 [8][6400][1152]    117,964,800   @ 13,107,200
  //   Wcb : bf16 [256][1152]            589,824   @ 131,072,000
  //   Wgt : f32  [81][128]               41,472   @ 131,661,824 (transposed)
  //   bgt : f32  [9][128]                 4,608   @ 131,703,296 (transposed)
  //   A2,B2: f32 [256] each               2,048   @ 131,707,904
  //   W1b : bf16 [128][256]              65,536   @ 131,709,952
  char* ws = (char*)d_ws;
  unsigned short* h   = (unsigned short*)ws;
  unsigned short* vt  = (unsigned short*)(ws + 13107200);
  unsigned short* Wcb = (unsigned short*)(ws + 131072000);
  float*          Wgt = (float*)(ws + 131661824);
  float*          bgt = (float*)(ws + 131703296);
  float*          A2  = (float*)(ws + 131707904);
  float*          B2  = A2 + C2_;
  unsigned short* W1b = (unsigned short*)(ws + 131709952);

  k0_prep<<<dim3((C2_ * CN_ + 255) / 256), 256, 0, stream>>>(
      Wc, bc, g2, b2, m2, v2, Wg, bg, gg, bgw, mg, vg, W1,
      Wcb, A2, B2, Wgt, bgt, W1b);

  dim3 grid1(HW_ / 64, B_);
  k1_cv1<<<grid1, 256, 0, stream>>>(x, W1b, g1, b1, m1, v1, h);

  dim3 grid2a(W_ / 8, H_, B_);
  k2a_weights<<<grid2a, 256, 0, stream>>>(h, Wgt, bgt, vt);

  dim3 grid2b(HW_ / 64, B_);
  k2b_gemm<<<grid2b, 512, 0, stream>>>(Wcb, vt, A2, B2, x, outp);
}